// Round 17
// baseline (127.946 us; speedup 1.0000x reference)
//
#include <hip/hip_runtime.h>

#define N_NODES 100000
#define N_EDGES 3200000
#define G_GRAPHS 512
#define HDIM 64
#define CBSH 11                 // 2048 nodes per coarse bucket
#define CBN 2048
#define NCB ((N_NODES + CBN - 1) / CBN)   // 49
#define EPW 4096                // edges per workgroup segment
#define NWG ((N_EDGES + EPW - 1) / EPW)   // 782
#define EPT (EPW / 256)         // 16
#define NWV 4                   // waves per binning block
#define SPL 8                   // splits per bucket in edge-reduce kernels
#define RTHR 512                // threads in reduce kernels (8 waves)
#define WPS ((NWG + SPL - 1) / SPL)       // 98 wgs per split
#define MAXROWS 25              // 1 + 4*6 table rows
#define ZBLK 1024               // zero/prep blocks appended to kBZ

// ---------------- kBZ: fused {edge binning | prep | zero} as disjoint block ranges
__global__ __launch_bounds__(256) void kBZ(const int* __restrict__ src,
                                           const int* __restrict__ dst,
                                           unsigned* __restrict__ sorted,
                                           int* __restrict__ wgcnt,
                                           int* __restrict__ wgpre,
                                           const float* __restrict__ W1,
                                           const float* __restrict__ b1,
                                           const float* __restrict__ W2,
                                           float* __restrict__ dt, int* __restrict__ meta,
                                           float* __restrict__ pw1, float* __restrict__ pb1,
                                           float* __restrict__ w2p, float* __restrict__ tabs,
                                           int* __restrict__ deg, float* __restrict__ q,
                                           float* __restrict__ pool, int* __restrict__ cnt,
                                           float* __restrict__ histA, float* __restrict__ histW) {
    int tid = threadIdx.x;
    if (blockIdx.x < NWG) {
        // ---- binning branch: per-wave hist/basep rows kill same-address serialization
        __shared__ int hist[NWV][NCB];
        __shared__ int basep[NWV][NCB];
        __shared__ unsigned sbuf[EPW];     // 16 KB
        int wv = tid >> 6;
        int w = blockIdx.x;
        int e0 = w * EPW;
        int ecnt = min(EPW, N_EDGES - e0);
        for (int i = tid; i < NWV * NCB; i += 256) (&hist[0][0])[i] = 0;
        __syncthreads();
        int dreg[EPT], sreg[EPT];
        const uint4* dst4 = reinterpret_cast<const uint4*>(dst + e0);
        const uint4* src4 = reinterpret_cast<const uint4*>(src + e0);
        #pragma unroll
        for (int t = 0; t < EPT / 4; ++t) {
            int v = t * 256 + tid;                       // vec4 index, coalesced
            if (v * 4 < ecnt) {
                uint4 dv = dst4[v];
                uint4 sv = src4[v];
                int base = v * 4;
                dreg[t*4+0] = (base+0 < ecnt) ? (int)dv.x : -1;
                dreg[t*4+1] = (base+1 < ecnt) ? (int)dv.y : -1;
                dreg[t*4+2] = (base+2 < ecnt) ? (int)dv.z : -1;
                dreg[t*4+3] = (base+3 < ecnt) ? (int)dv.w : -1;
                sreg[t*4+0] = (int)sv.x; sreg[t*4+1] = (int)sv.y;
                sreg[t*4+2] = (int)sv.z; sreg[t*4+3] = (int)sv.w;
                #pragma unroll
                for (int k = 0; k < 4; ++k)
                    if (dreg[t*4+k] >= 0) atomicAdd(&hist[wv][dreg[t*4+k] >> CBSH], 1);
            } else {
                dreg[t*4+0] = dreg[t*4+1] = dreg[t*4+2] = dreg[t*4+3] = -1;
            }
        }
        __syncthreads();
        if (tid < 64) {                                  // wave 0: totals + scan + wave bases
            int h0 = 0, h1 = 0, h2 = 0, h3 = 0;
            if (tid < NCB) { h0 = hist[0][tid]; h1 = hist[1][tid]; h2 = hist[2][tid]; h3 = hist[3][tid]; }
            int tot = h0 + h1 + h2 + h3;
            int v = tot;
            #pragma unroll
            for (int off = 1; off < 64; off <<= 1) {
                int uu = __shfl_up(v, off, 64);
                if (tid >= off) v += uu;
            }
            if (tid < NCB) {
                int base = v - tot;                      // exclusive prefix
                basep[0][tid] = base;
                basep[1][tid] = base + h0;
                basep[2][tid] = base + h0 + h1;
                basep[3][tid] = base + h0 + h1 + h2;
                wgcnt[w * NCB + tid] = tot;
                wgpre[w * NCB + tid] = base;
            }
        }
        __syncthreads();
        #pragma unroll
        for (int t = 0; t < EPT; ++t) {
            int d = dreg[t];
            if (d >= 0) {
                int b = d >> CBSH;
                int pos = atomicAdd(&basep[wv][b], 1);   // wave-private bump
                sbuf[pos] = ((unsigned)sreg[t] << CBSH) | (unsigned)(d & (CBN - 1));
            }
        }
        __syncthreads();
        uint4* out4 = reinterpret_cast<uint4*>(sorted + e0);
        const uint4* sb4 = reinterpret_cast<const uint4*>(sbuf);
        int nv4 = ecnt >> 2;
        for (int i = tid; i < nv4; i += 256) out4[i] = sb4[i];
        for (int i = (nv4 << 2) + tid; i < ecnt; i += 256) sorted[e0 + i] = sbuf[i];
        return;
    }
    // ---- prep branch (first 16 zero-blocks) + zero branch (all zero-blocks)
    int zb = blockIdx.x - NWG;                           // 0..ZBLK-1
    if (zb < 16) {
        __shared__ float ts[HDIM], srt[HDIM];
        __shared__ int isnew[HDIM], rr[HDIM], kpermS[HDIM], rankS[HDIM];
        __shared__ int ndS;
        if (tid < HDIM) {
            float w1 = W1[tid], bb = b1[tid];
            ts[tid] = (w1 != 0.f) ? (-bb / w1) : -1e30f;
        }
        __syncthreads();
        if (tid < HDIM) {
            float tj = ts[tid];
            int r = 0;
            for (int i = 0; i < HDIM; ++i) {
                float ti = ts[i];
                if (ti < tj || (ti == tj && i < tid)) r++;   // stable rank
            }
            rr[tid] = r;
            srt[r] = tj;
            kpermS[r] = tid;
        }
        __syncthreads();
        if (tid < HDIM) {
            int r = rr[tid];
            isnew[r] = (r == 0) || (srt[r] != srt[r - 1]);
        }
        __syncthreads();
        if (tid < HDIM) {
            int r = rr[tid];
            int didx = 0;
            for (int qq = 0; qq <= r; ++qq) didx += isnew[qq];
            didx -= 1;
            rankS[tid] = didx;
            if (zb == 0 && isnew[r]) dt[didx] = srt[r];
        }
        if (tid == 0) {
            int nd = 0;
            for (int qq = 0; qq < HDIM; ++qq) nd += isnew[qq];
            ndS = nd;
            if (zb == 0) {
                int nw = 0;
                for (int qq = 0; qq < HDIM; ++qq) nw |= (b1[qq] != 0.f) ? 1 : 0;
                meta[0] = nd; meta[1] = nw;
            }
        }
        __syncthreads();
        int nd = ndS;
        if (zb == 0 && tid < HDIM) {
            int pj = kpermS[tid];
            pw1[tid] = W1[pj]; pb1[tid] = b1[pj];
        }
        int i = zb * 256 + tid;
        if (i < HDIM * HDIM) {
            int r = i >> 6, j = i & 63;
            w2p[i] = W2[kpermS[r] * HDIM + j];
        }
        if (nd <= 6 && i < (1 + 4 * nd) * HDIM) {
            int r = i >> 6, j = i & 63;
            float acc = 0.f;
            if (r == 0) {
                for (int jj = 0; jj < HDIM; ++jj)
                    if (W1[jj] == 0.f) acc += fmaxf(b1[jj], 0.f) * W2[jj * HDIM + j];
            } else {
                int qq = (r - 1) >> 2, c = (r - 1) & 3;
                for (int jj = 0; jj < HDIM; ++jj) {
                    if (rankS[jj] != qq) continue;
                    float w1 = W1[jj], bb = b1[jj];
                    float wr = W2[jj * HDIM + j];
                    if      (c == 0 && w1 > 0.f) acc += w1 * wr;
                    else if (c == 1 && w1 < 0.f) acc += w1 * wr;
                    else if (c == 2 && w1 > 0.f) acc += bb * wr;
                    else if (c == 3 && w1 < 0.f) acc += bb * wr;
                }
            }
            tabs[i] = acc;
        }
    }
    // zero (grid-stride over zero-blocks)
    size_t gtid = (size_t)zb * 256 + tid;
    size_t stride = (size_t)ZBLK * 256;
    for (size_t i = gtid; i < N_NODES; i += stride) { deg[i] = 0; q[i] = 0.f; }
    for (size_t i = gtid; i < G_GRAPHS * HDIM; i += stride) pool[i] = 0.f;
    for (size_t i = gtid; i < G_GRAPHS; i += stride) cnt[i] = 0;
    size_t nh = (size_t)7 * N_NODES;
    for (size_t i = gtid; i < nh; i += stride) { histA[i] = 0.f; histW[i] = 0.f; }
}

// helper macro: iterate this split's runs for bucket b, wave-per-run
#define FOR_RUNS(BODY)                                                        \
    {                                                                         \
        int wv = tid >> 6, ln = tid & 63;                                     \
        int w0 = sp * WPS, w1e = min(w0 + WPS, NWG);                          \
        for (int w = w0 + wv; w < w1e; w += (RTHR / 64)) {                    \
            int st = w * EPW + wgpre[w * NCB + b];                            \
            int cb = wgcnt[w * NCB + b];                                      \
            for (int i = ln; i < cb; i += 64) { unsigned ww = sorted[st + i]; BODY } \
        }                                                                     \
    }

// ---------------- kdeg2: split LDS degree count + coalesced atomic merge
__global__ __launch_bounds__(RTHR) void kdeg2(const unsigned* __restrict__ sorted,
                                              const int* __restrict__ wgcnt,
                                              const int* __restrict__ wgpre,
                                              int* __restrict__ deg) {
    __shared__ int dcnt[CBN];
    int b = blockIdx.x / SPL, sp = blockIdx.x % SPL, tid = threadIdx.x;
    for (int i = tid; i < CBN; i += RTHR) dcnt[i] = 0;
    __syncthreads();
    FOR_RUNS( atomicAdd(&dcnt[ww & (CBN - 1)], 1); )
    __syncthreads();
    int nb = b * CBN;
    for (int i = tid; i < CBN; i += RTHR) {
        int c = dcnt[i];
        if (c && nb + i < N_NODES) atomicAdd(&deg[nb + i], c);
    }
}

// ---------------- k2_dis: dis = rsqrt(deg+1); u = dis*x
__global__ void k2_dis(const int* __restrict__ deg, const float* __restrict__ x,
                       float* __restrict__ dis, float* __restrict__ u) {
    int n = blockIdx.x * blockDim.x + threadIdx.x;
    if (n < N_NODES) {
        float d = rsqrtf((float)(deg[n] + 1));
        dis[n] = d;
        u[n] = d * x[n];
    }
}

// ---------------- kq3: split LDS layer-1 reduce + coalesced atomic merge
__global__ __launch_bounds__(RTHR) void kq3(const unsigned* __restrict__ sorted,
                                            const int* __restrict__ wgcnt,
                                            const int* __restrict__ wgpre,
                                            const float* __restrict__ u,
                                            float* __restrict__ q) {
    __shared__ float qL[CBN];
    int b = blockIdx.x / SPL, sp = blockIdx.x % SPL, tid = threadIdx.x;
    for (int i = tid; i < CBN; i += RTHR) qL[i] = 0.f;
    __syncthreads();
    FOR_RUNS( atomicAdd(&qL[ww & (CBN - 1)], u[ww >> CBSH]); )
    __syncthreads();
    int nb = b * CBN;
    for (int i = tid; i < CBN; i += RTHR) {
        float v = qL[i];
        if (v != 0.f && nb + i < N_NODES) atomicAdd(&q[nb + i], v);
    }
}

// ---------------- k3b: finalize (agg1, dis) pack
__global__ void k3b(const int* __restrict__ deg, const float* __restrict__ x,
                    const float* __restrict__ dis, const float* __restrict__ q,
                    float2* __restrict__ ad) {
    int n = blockIdx.x * blockDim.x + threadIdx.x;
    if (n < N_NODES) {
        float d = dis[n];
        ad[n] = make_float2(d * q[n] + x[n] / (float)(deg[n] + 1), d);
    }
}

// ---------------- khist: split LDS bucket-sums (single variant, 7 planes, ad gather)
__global__ __launch_bounds__(RTHR) void khist(const unsigned* __restrict__ sorted,
                                              const int* __restrict__ wgcnt,
                                              const int* __restrict__ wgpre,
                                              const float2* __restrict__ ad,
                                              const float* __restrict__ dt,
                                              const int* __restrict__ meta,
                                              float* __restrict__ histA,
                                              float* __restrict__ histW) {
    __shared__ float bA[7 * CBN];          // 56 KB
    __shared__ float dtS[8];
    int nd = meta[0], needW = meta[1];
    if (nd > 6) return;                    // knode general path covers
    int b = blockIdx.x / SPL, sp = blockIdx.x % SPL, tid = threadIdx.x;
    if (tid < 8) dtS[tid] = (tid < nd) ? dt[tid] : 3.4e38f;
    int nb = b * CBN;
    int nparts = 1 + (needW ? 1 : 0);
    for (int part = 0; part < nparts; ++part) {
        for (int i = tid; i < (nd + 1) * CBN; i += RTHR) bA[i] = 0.f;
        __syncthreads();
        FOR_RUNS(
            float2 t = ad[ww >> CBSH];
            float a = t.x;
            int k = 0;
            _Pragma("unroll")
            for (int qq = 0; qq < 6; ++qq) k += (dtS[qq] < a) ? 1 : 0;
            atomicAdd(&bA[k * CBN + (ww & (CBN - 1))], part ? t.y : t.y * a);
        )
        __syncthreads();
        float* H = part ? histW : histA;
        for (int k = 0; k <= nd; ++k)
            for (int i = tid; i < CBN; i += RTHR) {
                float v = bA[k * CBN + i];
                if (v != 0.f && nb + i < N_NODES)
                    atomicAdd(&H[(size_t)k * N_NODES + nb + i], v);
            }
        __syncthreads();
    }
}

// ---- knode: fast table-folded path (nd<=6) + LDS-staged general path (nd>6)
__global__ __launch_bounds__(256) void knode(
        const float* __restrict__ histA, const float* __restrict__ histW,
        const int* __restrict__ meta, const float* __restrict__ dt,
        const float* __restrict__ tabs,
        const float* __restrict__ pw1, const float* __restrict__ pb1,
        const float* __restrict__ w2p,
        const float2* __restrict__ ad, const float* __restrict__ b2,
        const int* __restrict__ batch,
        const unsigned* __restrict__ sorted, const int* __restrict__ wgcnt,
        const int* __restrict__ wgpre,
        float* __restrict__ pool, int* __restrict__ cnt) {
    __shared__ float h2s[HDIM * 65];
    __shared__ float tabL[MAXROWS * HDIM];
    __shared__ float dtS[8];
    int tid = threadIdx.x;
    int nl = tid & 63, cg = tid >> 6;
    int n0 = blockIdx.x * 64;
    int nvalid = min(64, N_NODES - n0);
    int n = n0 + min(nl, nvalid - 1);
    int nd = meta[0], needW = meta[1];
    float2 adn = ad[n];
    float a = adn.x, d = adn.y;
    int c16 = cg * 16;

    if (nd <= 6) {
        int nrows = 1 + 4 * nd;
        for (int i = tid; i < nrows * HDIM; i += 256) tabL[i] = tabs[i];
        if (tid < nd) dtS[tid] = dt[tid];
        __syncthreads();
        float TA = 0.f, TW = 0.f;
        for (int bq = 0; bq <= nd; ++bq) {
            TA += histA[(size_t)bq * N_NODES + n];
            if (needW) TW += histW[(size_t)bq * N_NODES + n];
        }
        int k = 0;
        for (int q = 0; q < nd; ++q) k += (dtS[q] < a) ? 1 : 0;
        float z[16];
        #pragma unroll
        for (int t = 0; t < 16; ++t) z[t] = b2[c16 + t];
        float d2 = d * d;
        float cC = d * TW + d2;
        #pragma unroll
        for (int t = 0; t < 16; ++t) z[t] += cC * tabL[c16 + t];
        float run = 0.f, runW = 0.f;
        for (int q = 0; q < nd; ++q) {
            run += histA[(size_t)q * N_NODES + n];
            if (needW) runW += histW[(size_t)q * N_NODES + n];
            bool act = (q < k);
            float cWp = d * (TA - run) + (act ? d2 * a : 0.f);
            float cWm = d * run + (act ? 0.f : d2 * a);
            float cBp = d * (TW - runW) + (act ? d2 : 0.f);
            float cBm = d * runW + (act ? 0.f : d2);
            int base = (1 + 4 * q) * HDIM + c16;
            #pragma unroll
            for (int t = 0; t < 16; ++t)
                z[t] += cWp * tabL[base + t] + cWm * tabL[base + HDIM + t]
                      + cBp * tabL[base + 2 * HDIM + t] + cBm * tabL[base + 3 * HDIM + t];
        }
        #pragma unroll
        for (int t = 0; t < 16; ++t) h2s[nl * 65 + c16 + t] = fmaxf(z[t], 0.f);
    } else {
        // general path (correctness-only): stage areg slices through h2s
        float zz[16];
        #pragma unroll
        for (int t = 0; t < 16; ++t) zz[t] = 0.f;
        int b = n >> CBSH;                           // uniform across block
        int myld = n & (CBN - 1);
        for (int w = 0; w < NWG; ++w) {
            int st = w * EPW + wgpre[w * NCB + b];
            int cb = wgcnt[w * NCB + b];
            for (int i = 0; i < cb; ++i) {
                unsigned ww = sorted[st + i];
                if ((int)(ww & (CBN - 1)) == myld) {
                    float2 t2 = ad[ww >> CBSH];
                    #pragma unroll
                    for (int t = 0; t < 16; ++t)
                        zz[t] += t2.y * fmaxf(t2.x * pw1[c16 + t] + pb1[c16 + t], 0.f);
                }
            }
        }
        #pragma unroll
        for (int t = 0; t < 16; ++t)
            zz[t] = d * zz[t] + d * d * fmaxf(a * pw1[c16 + t] + pb1[c16 + t], 0.f);
        #pragma unroll
        for (int t = 0; t < 16; ++t) h2s[nl * 65 + c16 + t] = zz[t];   // areg staging
        __syncthreads();
        float z[16];
        #pragma unroll
        for (int t = 0; t < 16; ++t) z[t] = b2[c16 + t];
        for (int jj = 0; jj < HDIM; ++jj) {
            float av = h2s[nl * 65 + jj];
            #pragma unroll
            for (int t = 0; t < 16; ++t) z[t] += av * w2p[jj * HDIM + c16 + t];
        }
        __syncthreads();
        #pragma unroll
        for (int t = 0; t < 16; ++t) h2s[nl * 65 + c16 + t] = fmaxf(z[t], 0.f);
    }

    __syncthreads();
    int i0 = cg * 16, i1 = min(i0 + 16, nvalid);
    float accP = 0.f; int gcur = -1, runC = 0;
    for (int i = i0; i < i1; ++i) {
        int g = batch[n0 + i];
        float v = h2s[i * 65 + nl];
        if (g != gcur) {
            if (gcur >= 0) {
                atomicAdd(&pool[(size_t)gcur * HDIM + nl], accP);
                if (nl == 0) atomicAdd(&cnt[gcur], runC);
            }
            gcur = g; accP = 0.f; runC = 0;
        }
        accP += v; ++runC;
    }
    if (gcur >= 0) {
        atomicAdd(&pool[(size_t)gcur * HDIM + nl], accP);
        if (nl == 0) atomicAdd(&cnt[gcur], runC);
    }
}

// ---------------- final MLP per graph
__global__ void k7_mlp(const float* __restrict__ pool, const int* __restrict__ cnt,
                       const float* __restrict__ fW1, const float* __restrict__ fb1,
                       const float* __restrict__ fW2, const float* __restrict__ fb2,
                       float* __restrict__ out) {
    __shared__ float p[HDIM];
    __shared__ float tt[32];
    int g = blockIdx.x;
    int tid = threadIdx.x;
    float c = fmaxf((float)cnt[g], 1.f);
    p[tid] = pool[g * HDIM + tid] / c;
    __syncthreads();
    if (tid < 32) {
        float acc = fb1[tid];
        #pragma unroll
        for (int j = 0; j < HDIM; ++j) acc += p[j] * fW1[j * 32 + tid];
        tt[tid] = fmaxf(acc, 0.f);
    }
    __syncthreads();
    if (tid < 7) {
        float acc = fb2[tid];
        #pragma unroll
        for (int i = 0; i < 32; ++i) acc += tt[i] * fW2[i * 7 + tid];
        out[g * 7 + tid] = acc;
    }
}

// =================== fallback path (round-1 kernels, if ws too small) ===================
__global__ void kf1_deg(const int* __restrict__ dst, int* __restrict__ deg) {
    int e = blockIdx.x * blockDim.x + threadIdx.x;
    if (e < N_EDGES) atomicAdd(&deg[dst[e]], 1);
}
__global__ void kf2_dis(const int* __restrict__ deg, const float* __restrict__ x,
                        float* __restrict__ dis, float* __restrict__ agg1) {
    int n = blockIdx.x * blockDim.x + threadIdx.x;
    if (n < N_NODES) {
        float d = (float)(deg[n] + 1);
        dis[n] = rsqrtf(d);
        agg1[n] = x[n] / d;
    }
}
__global__ void kf3_agg1(const int* __restrict__ src, const int* __restrict__ dst,
                         const float* __restrict__ dis, const float* __restrict__ x,
                         float* __restrict__ agg1) {
    int e = blockIdx.x * blockDim.x + threadIdx.x;
    if (e < N_EDGES) {
        int s = src[e], d = dst[e];
        atomicAdd(&agg1[d], dis[s] * dis[d] * x[s]);
    }
}
__global__ void kf4_agg2init(const float* __restrict__ agg1, const float* __restrict__ dis,
                             const float* __restrict__ W1, const float* __restrict__ b1,
                             float* __restrict__ agg2) {
    int i = blockIdx.x * blockDim.x + threadIdx.x;
    if (i < N_NODES * HDIM) {
        int n = i >> 6, j = i & 63;
        float h = fmaxf(agg1[n] * W1[j] + b1[j], 0.f);
        float r = dis[n];
        agg2[i] = r * r * h;
    }
}
__global__ void kf5_edge(const int* __restrict__ src, const int* __restrict__ dst,
                         const float* __restrict__ dis, const float* __restrict__ agg1,
                         const float* __restrict__ W1, const float* __restrict__ b1,
                         float* __restrict__ agg2) {
    int t = blockIdx.x * blockDim.x + threadIdx.x;
    int e = t >> 6, j = t & 63;
    if (e < N_EDGES) {
        int s = src[e], d = dst[e];
        float w = dis[s] * dis[d];
        float h = fmaxf(agg1[s] * W1[j] + b1[j], 0.f);
        atomicAdd(&agg2[d * HDIM + j], w * h);
    }
}
__global__ void kf6_pool(const float* __restrict__ agg2, const float* __restrict__ W2,
                         const float* __restrict__ b2, const int* __restrict__ batch,
                         float* __restrict__ pool, int* __restrict__ cnt) {
    __shared__ float w2s[HDIM * HDIM];
    int tid = threadIdx.x;
    for (int i = tid; i < HDIM * HDIM; i += blockDim.x) w2s[i] = W2[i];
    __syncthreads();
    int lane = tid & 63, wid = tid >> 6;
    int nwaves = gridDim.x * 4;
    for (int n = blockIdx.x * 4 + wid; n < N_NODES; n += nwaves) {
        float av  = agg2[n * HDIM + lane];
        float acc = b2[lane];
        #pragma unroll
        for (int k = 0; k < HDIM; ++k)
            acc += __shfl(av, k, 64) * w2s[k * HDIM + lane];
        acc = fmaxf(acc, 0.f);
        int g = batch[n];
        atomicAdd(&pool[g * HDIM + lane], acc);
        if (lane == 0) atomicAdd(&cnt[g], 1);
    }
}

// ----------------------------------------------------------------------------
extern "C" void kernel_launch(void* const* d_in, const int* in_sizes, int n_in,
                              void* d_out, int out_size, void* d_ws, size_t ws_size,
                              hipStream_t stream) {
    const float* x    = (const float*)d_in[0];
    const int*   ei   = (const int*)  d_in[1];
    const int*   batch= (const int*)  d_in[2];
    const float* W1   = (const float*)d_in[3];
    const float* b1   = (const float*)d_in[4];
    const float* W2   = (const float*)d_in[5];
    const float* b2   = (const float*)d_in[6];
    const float* fW1  = (const float*)d_in[7];
    const float* fb1  = (const float*)d_in[8];
    const float* fW2  = (const float*)d_in[9];
    const float* fb2  = (const float*)d_in[10];
    const int* src = ei;
    const int* dst = ei + N_EDGES;
    float* out = (float*)d_out;

    size_t off = 0;
    auto take = [&](size_t bytes) { size_t o = off; off = (off + bytes + 255) & ~(size_t)255; return o; };
    char* base = (char*)d_ws;
    int*     deg   = (int*)     (base + take((size_t)N_NODES * 4));
    float*   pool  = (float*)   (base + take((size_t)G_GRAPHS * HDIM * 4));
    int*     cnt   = (int*)     (base + take((size_t)G_GRAPHS * 4));
    float*   dis   = (float*)   (base + take((size_t)N_NODES * 4));
    float*   u     = (float*)   (base + take((size_t)N_NODES * 4));
    float*   q     = (float*)   (base + take((size_t)N_NODES * 4));
    float2*  ad    = (float2*)  (base + take((size_t)N_NODES * 8));
    float*   dt    = (float*)   (base + take(HDIM * 4));
    int*     meta  = (int*)     (base + take(64));
    float*   pw1   = (float*)   (base + take(HDIM * 4));
    float*   pb1   = (float*)   (base + take(HDIM * 4));
    float*   w2p   = (float*)   (base + take(HDIM * HDIM * 4));
    float*   tabs  = (float*)   (base + take((size_t)MAXROWS * HDIM * 4));
    int*     wgcnt = (int*)     (base + take((size_t)NWG * NCB * 4));
    int*     wgpre = (int*)     (base + take((size_t)NWG * NCB * 4));
    size_t sorted_off = off;
    unsigned* sorted = (unsigned*)(base + take((size_t)N_EDGES * 4));
    float*   histA = (float*)   (base + take((size_t)7 * N_NODES * 4));
    float*   histW = (float*)   (base + take((size_t)7 * N_NODES * 4));
    size_t need_fast = off;

    if (ws_size >= need_fast) {
        kBZ   <<<NWG + ZBLK, 256, 0, stream>>>(src, dst, sorted, wgcnt, wgpre,
                                               W1, b1, W2, dt, meta, pw1, pb1, w2p, tabs,
                                               deg, q, pool, cnt, histA, histW);
        kdeg2 <<<NCB * SPL, RTHR, 0, stream>>>(sorted, wgcnt, wgpre, deg);
        k2_dis<<<(N_NODES + 255) / 256, 256, 0, stream>>>(deg, x, dis, u);
        kq3   <<<NCB * SPL, RTHR, 0, stream>>>(sorted, wgcnt, wgpre, u, q);
        k3b   <<<(N_NODES + 255) / 256, 256, 0, stream>>>(deg, x, dis, q, ad);
        khist <<<NCB * SPL, RTHR, 0, stream>>>(sorted, wgcnt, wgpre, ad, dt, meta, histA, histW);
        knode <<<(N_NODES + 63) / 64, 256, 0, stream>>>(histA, histW, meta, dt, tabs,
                                                        pw1, pb1, w2p, ad, b2, batch,
                                                        sorted, wgcnt, wgpre, pool, cnt);
        k7_mlp<<<G_GRAPHS, 64, 0, stream>>>(pool, cnt, fW1, fb1, fW2, fb2, out);
    } else {
        // fallback: R1 pipeline; agg1 in u, agg2 in the sorted/hist region
        float* agg1 = u;
        float* agg2 = (float*)(base + sorted_off);
        hipMemsetAsync(deg, 0, (size_t)N_NODES * 4, stream);
        hipMemsetAsync(pool, 0, (size_t)G_GRAPHS * HDIM * 4 + 1024, stream);
        kf1_deg<<<(N_EDGES + 255) / 256, 256, 0, stream>>>(dst, deg);
        kf2_dis<<<(N_NODES + 255) / 256, 256, 0, stream>>>(deg, x, dis, agg1);
        kf3_agg1<<<(N_EDGES + 255) / 256, 256, 0, stream>>>(src, dst, dis, x, agg1);
        kf4_agg2init<<<(N_NODES * HDIM + 255) / 256, 256, 0, stream>>>(agg1, dis, W1, b1, agg2);
        int k5_blocks = (int)(((long long)N_EDGES * HDIM + 255) / 256);
        kf5_edge<<<k5_blocks, 256, 0, stream>>>(src, dst, dis, agg1, W1, b1, agg2);
        kf6_pool<<<2048, 256, 0, stream>>>(agg2, W2, b2, batch, pool, cnt);
        k7_mlp<<<G_GRAPHS, 64, 0, stream>>>(pool, cnt, fW1, fb1, fW2, fb2, out);
    }
}

// Round 18
// 127.182 us; speedup vs baseline: 1.0060x; 1.0060x over previous
//
#include <hip/hip_runtime.h>

#define N_NODES 100000
#define N_EDGES 3200000
#define G_GRAPHS 512
#define HDIM 64
#define CBSH 11                 // 2048 nodes per coarse bucket
#define CBN 2048
#define NCB ((N_NODES + CBN - 1) / CBN)   // 49
#define EPW 4096                // edges per workgroup segment
#define NWG ((N_EDGES + EPW - 1) / EPW)   // 782
#define NWV 4                   // waves per binning block
#define SPL 8                   // splits per bucket in edge-reduce kernels
#define RTHR 512                // threads in reduce kernels (8 waves)
#define WPS ((NWG + SPL - 1) / SPL)       // 98 wgs per split
#define MAXROWS 25              // 1 + 4*6 table rows
#define ZBLK 1024               // zero/prep blocks appended to kBZ

// ---------------- kBZ: fused {edge binning | prep | zero} as disjoint block ranges
// binning branch: NO per-thread edge caches (reload L2-hot in scatter phase) -> no spill
__global__ __launch_bounds__(256) void kBZ(const int* __restrict__ src,
                                           const int* __restrict__ dst,
                                           unsigned* __restrict__ sorted,
                                           int* __restrict__ wgcnt,
                                           int* __restrict__ wgpre,
                                           const float* __restrict__ W1,
                                           const float* __restrict__ b1,
                                           const float* __restrict__ W2,
                                           float* __restrict__ dt, int* __restrict__ meta,
                                           float* __restrict__ pw1, float* __restrict__ pb1,
                                           float* __restrict__ w2p, float* __restrict__ tabs,
                                           int* __restrict__ deg, float* __restrict__ q,
                                           float* __restrict__ pool, int* __restrict__ cnt,
                                           float* __restrict__ histA, float* __restrict__ histW) {
    int tid = threadIdx.x;
    if (blockIdx.x < NWG) {
        __shared__ int hist[NWV][NCB];
        __shared__ int basep[NWV][NCB];
        __shared__ unsigned sbuf[EPW];     // 16 KB
        int wv = tid >> 6;
        int w = blockIdx.x;
        int e0 = w * EPW;
        int ecnt = min(EPW, N_EDGES - e0);           // always a multiple of 4
        int nv4 = ecnt >> 2;
        for (int i = tid; i < NWV * NCB; i += 256) (&hist[0][0])[i] = 0;
        __syncthreads();
        const uint4* dst4 = reinterpret_cast<const uint4*>(dst + e0);
        const uint4* src4 = reinterpret_cast<const uint4*>(src + e0);
        // phase 1: histogram (keep nothing)
        for (int v = tid; v < nv4; v += 256) {
            uint4 dv = dst4[v];
            atomicAdd(&hist[wv][dv.x >> CBSH], 1);
            atomicAdd(&hist[wv][dv.y >> CBSH], 1);
            atomicAdd(&hist[wv][dv.z >> CBSH], 1);
            atomicAdd(&hist[wv][dv.w >> CBSH], 1);
        }
        __syncthreads();
        if (tid < 64) {                              // wave 0: totals + scan + wave bases
            int h0 = 0, h1 = 0, h2 = 0, h3 = 0;
            if (tid < NCB) { h0 = hist[0][tid]; h1 = hist[1][tid]; h2 = hist[2][tid]; h3 = hist[3][tid]; }
            int tot = h0 + h1 + h2 + h3;
            int v = tot;
            #pragma unroll
            for (int off = 1; off < 64; off <<= 1) {
                int uu = __shfl_up(v, off, 64);
                if (tid >= off) v += uu;
            }
            if (tid < NCB) {
                int base = v - tot;                  // exclusive prefix
                basep[0][tid] = base;
                basep[1][tid] = base + h0;
                basep[2][tid] = base + h0 + h1;
                basep[3][tid] = base + h0 + h1 + h2;
                wgcnt[w * NCB + tid] = tot;
                wgpre[w * NCB + tid] = base;
            }
        }
        __syncthreads();
        // phase 3: reload (L2-hot) and scatter into sbuf
        for (int v = tid; v < nv4; v += 256) {
            uint4 dv = dst4[v];
            uint4 sv = src4[v];
            int b, pos;
            b = (int)(dv.x >> CBSH); pos = atomicAdd(&basep[wv][b], 1);
            sbuf[pos] = (sv.x << CBSH) | (dv.x & (CBN - 1));
            b = (int)(dv.y >> CBSH); pos = atomicAdd(&basep[wv][b], 1);
            sbuf[pos] = (sv.y << CBSH) | (dv.y & (CBN - 1));
            b = (int)(dv.z >> CBSH); pos = atomicAdd(&basep[wv][b], 1);
            sbuf[pos] = (sv.z << CBSH) | (dv.z & (CBN - 1));
            b = (int)(dv.w >> CBSH); pos = atomicAdd(&basep[wv][b], 1);
            sbuf[pos] = (sv.w << CBSH) | (dv.w & (CBN - 1));
        }
        __syncthreads();
        uint4* out4 = reinterpret_cast<uint4*>(sorted + e0);
        const uint4* sb4 = reinterpret_cast<const uint4*>(sbuf);
        for (int i = tid; i < nv4; i += 256) out4[i] = sb4[i];
        return;
    }
    // ---- prep branch (first 16 zero-blocks) + zero branch (all zero-blocks)
    int zb = blockIdx.x - NWG;                           // 0..ZBLK-1
    if (zb < 16) {
        __shared__ float ts[HDIM], srt[HDIM];
        __shared__ int isnew[HDIM], rr[HDIM], kpermS[HDIM], rankS[HDIM];
        __shared__ int ndS;
        if (tid < HDIM) {
            float w1 = W1[tid], bb = b1[tid];
            ts[tid] = (w1 != 0.f) ? (-bb / w1) : -1e30f;
        }
        __syncthreads();
        if (tid < HDIM) {
            float tj = ts[tid];
            int r = 0;
            for (int i = 0; i < HDIM; ++i) {
                float ti = ts[i];
                if (ti < tj || (ti == tj && i < tid)) r++;   // stable rank
            }
            rr[tid] = r;
            srt[r] = tj;
            kpermS[r] = tid;
        }
        __syncthreads();
        if (tid < HDIM) {
            int r = rr[tid];
            isnew[r] = (r == 0) || (srt[r] != srt[r - 1]);
        }
        __syncthreads();
        if (tid < HDIM) {
            int r = rr[tid];
            int didx = 0;
            for (int qq = 0; qq <= r; ++qq) didx += isnew[qq];
            didx -= 1;
            rankS[tid] = didx;
            if (zb == 0 && isnew[r]) dt[didx] = srt[r];
        }
        if (tid == 0) {
            int nd = 0;
            for (int qq = 0; qq < HDIM; ++qq) nd += isnew[qq];
            ndS = nd;
            if (zb == 0) {
                int nw = 0;
                for (int qq = 0; qq < HDIM; ++qq) nw |= (b1[qq] != 0.f) ? 1 : 0;
                meta[0] = nd; meta[1] = nw;
            }
        }
        __syncthreads();
        int nd = ndS;
        if (zb == 0 && tid < HDIM) {
            int pj = kpermS[tid];
            pw1[tid] = W1[pj]; pb1[tid] = b1[pj];
        }
        int i = zb * 256 + tid;
        if (i < HDIM * HDIM) {
            int r = i >> 6, j = i & 63;
            w2p[i] = W2[kpermS[r] * HDIM + j];
        }
        if (nd <= 6 && i < (1 + 4 * nd) * HDIM) {
            int r = i >> 6, j = i & 63;
            float acc = 0.f;
            if (r == 0) {
                for (int jj = 0; jj < HDIM; ++jj)
                    if (W1[jj] == 0.f) acc += fmaxf(b1[jj], 0.f) * W2[jj * HDIM + j];
            } else {
                int qq = (r - 1) >> 2, c = (r - 1) & 3;
                for (int jj = 0; jj < HDIM; ++jj) {
                    if (rankS[jj] != qq) continue;
                    float w1 = W1[jj], bb = b1[jj];
                    float wr = W2[jj * HDIM + j];
                    if      (c == 0 && w1 > 0.f) acc += w1 * wr;
                    else if (c == 1 && w1 < 0.f) acc += w1 * wr;
                    else if (c == 2 && w1 > 0.f) acc += bb * wr;
                    else if (c == 3 && w1 < 0.f) acc += bb * wr;
                }
            }
            tabs[i] = acc;
        }
    }
    // zero (grid-stride over zero-blocks)
    size_t gtid = (size_t)zb * 256 + tid;
    size_t stride = (size_t)ZBLK * 256;
    for (size_t i = gtid; i < N_NODES; i += stride) { deg[i] = 0; q[i] = 0.f; }
    for (size_t i = gtid; i < G_GRAPHS * HDIM; i += stride) pool[i] = 0.f;
    for (size_t i = gtid; i < G_GRAPHS; i += stride) cnt[i] = 0;
    size_t nh = (size_t)7 * N_NODES;
    for (size_t i = gtid; i < nh; i += stride) { histA[i] = 0.f; histW[i] = 0.f; }
}

// helper macro: iterate this split's runs for bucket b, wave-per-run
#define FOR_RUNS(BODY)                                                        \
    {                                                                         \
        int wv = tid >> 6, ln = tid & 63;                                     \
        int w0 = sp * WPS, w1e = min(w0 + WPS, NWG);                          \
        for (int w = w0 + wv; w < w1e; w += (RTHR / 64)) {                    \
            int st = w * EPW + wgpre[w * NCB + b];                            \
            int cb = wgcnt[w * NCB + b];                                      \
            for (int i = ln; i < cb; i += 64) { unsigned ww = sorted[st + i]; BODY } \
        }                                                                     \
    }

// ---------------- kdeg2: split LDS degree count + coalesced atomic merge
__global__ __launch_bounds__(RTHR) void kdeg2(const unsigned* __restrict__ sorted,
                                              const int* __restrict__ wgcnt,
                                              const int* __restrict__ wgpre,
                                              int* __restrict__ deg) {
    __shared__ int dcnt[CBN];
    int b = blockIdx.x / SPL, sp = blockIdx.x % SPL, tid = threadIdx.x;
    for (int i = tid; i < CBN; i += RTHR) dcnt[i] = 0;
    __syncthreads();
    FOR_RUNS( atomicAdd(&dcnt[ww & (CBN - 1)], 1); )
    __syncthreads();
    int nb = b * CBN;
    for (int i = tid; i < CBN; i += RTHR) {
        int c = dcnt[i];
        if (c && nb + i < N_NODES) atomicAdd(&deg[nb + i], c);
    }
}

// ---------------- k2_dis: dis = rsqrt(deg+1); u = dis*x
__global__ void k2_dis(const int* __restrict__ deg, const float* __restrict__ x,
                       float* __restrict__ dis, float* __restrict__ u) {
    int n = blockIdx.x * blockDim.x + threadIdx.x;
    if (n < N_NODES) {
        float d = rsqrtf((float)(deg[n] + 1));
        dis[n] = d;
        u[n] = d * x[n];
    }
}

// ---------------- kq3: split LDS layer-1 reduce + coalesced atomic merge
__global__ __launch_bounds__(RTHR) void kq3(const unsigned* __restrict__ sorted,
                                            const int* __restrict__ wgcnt,
                                            const int* __restrict__ wgpre,
                                            const float* __restrict__ u,
                                            float* __restrict__ q) {
    __shared__ float qL[CBN];
    int b = blockIdx.x / SPL, sp = blockIdx.x % SPL, tid = threadIdx.x;
    for (int i = tid; i < CBN; i += RTHR) qL[i] = 0.f;
    __syncthreads();
    FOR_RUNS( atomicAdd(&qL[ww & (CBN - 1)], u[ww >> CBSH]); )
    __syncthreads();
    int nb = b * CBN;
    for (int i = tid; i < CBN; i += RTHR) {
        float v = qL[i];
        if (v != 0.f && nb + i < N_NODES) atomicAdd(&q[nb + i], v);
    }
}

// ---------------- k3b: finalize (agg1, dis) pack
__global__ void k3b(const int* __restrict__ deg, const float* __restrict__ x,
                    const float* __restrict__ dis, const float* __restrict__ q,
                    float2* __restrict__ ad) {
    int n = blockIdx.x * blockDim.x + threadIdx.x;
    if (n < N_NODES) {
        float d = dis[n];
        ad[n] = make_float2(d * q[n] + x[n] / (float)(deg[n] + 1), d);
    }
}

// ---------------- khist: split LDS bucket-sums (single variant, 7 planes, ad gather)
__global__ __launch_bounds__(RTHR) void khist(const unsigned* __restrict__ sorted,
                                              const int* __restrict__ wgcnt,
                                              const int* __restrict__ wgpre,
                                              const float2* __restrict__ ad,
                                              const float* __restrict__ dt,
                                              const int* __restrict__ meta,
                                              float* __restrict__ histA,
                                              float* __restrict__ histW) {
    __shared__ float bA[7 * CBN];          // 56 KB
    __shared__ float dtS[8];
    int nd = meta[0], needW = meta[1];
    if (nd > 6) return;                    // knode general path covers
    int b = blockIdx.x / SPL, sp = blockIdx.x % SPL, tid = threadIdx.x;
    if (tid < 8) dtS[tid] = (tid < nd) ? dt[tid] : 3.4e38f;
    int nb = b * CBN;
    int nparts = 1 + (needW ? 1 : 0);
    for (int part = 0; part < nparts; ++part) {
        for (int i = tid; i < (nd + 1) * CBN; i += RTHR) bA[i] = 0.f;
        __syncthreads();
        FOR_RUNS(
            float2 t = ad[ww >> CBSH];
            float a = t.x;
            int k = 0;
            _Pragma("unroll")
            for (int qq = 0; qq < 6; ++qq) k += (dtS[qq] < a) ? 1 : 0;
            atomicAdd(&bA[k * CBN + (ww & (CBN - 1))], part ? t.y : t.y * a);
        )
        __syncthreads();
        float* H = part ? histW : histA;
        for (int k = 0; k <= nd; ++k)
            for (int i = tid; i < CBN; i += RTHR) {
                float v = bA[k * CBN + i];
                if (v != 0.f && nb + i < N_NODES)
                    atomicAdd(&H[(size_t)k * N_NODES + nb + i], v);
            }
        __syncthreads();
    }
}

// ---- knode: fast table-folded path (nd<=6) + LDS-staged general path (nd>6)
__global__ __launch_bounds__(256) void knode(
        const float* __restrict__ histA, const float* __restrict__ histW,
        const int* __restrict__ meta, const float* __restrict__ dt,
        const float* __restrict__ tabs,
        const float* __restrict__ pw1, const float* __restrict__ pb1,
        const float* __restrict__ w2p,
        const float2* __restrict__ ad, const float* __restrict__ b2,
        const int* __restrict__ batch,
        const unsigned* __restrict__ sorted, const int* __restrict__ wgcnt,
        const int* __restrict__ wgpre,
        float* __restrict__ pool, int* __restrict__ cnt) {
    __shared__ float h2s[HDIM * 65];
    __shared__ float tabL[MAXROWS * HDIM];
    __shared__ float dtS[8];
    int tid = threadIdx.x;
    int nl = tid & 63, cg = tid >> 6;
    int n0 = blockIdx.x * 64;
    int nvalid = min(64, N_NODES - n0);
    int n = n0 + min(nl, nvalid - 1);
    int nd = meta[0], needW = meta[1];
    float2 adn = ad[n];
    float a = adn.x, d = adn.y;
    int c16 = cg * 16;

    if (nd <= 6) {
        int nrows = 1 + 4 * nd;
        for (int i = tid; i < nrows * HDIM; i += 256) tabL[i] = tabs[i];
        if (tid < nd) dtS[tid] = dt[tid];
        __syncthreads();
        float TA = 0.f, TW = 0.f;
        for (int bq = 0; bq <= nd; ++bq) {
            TA += histA[(size_t)bq * N_NODES + n];
            if (needW) TW += histW[(size_t)bq * N_NODES + n];
        }
        int k = 0;
        for (int q = 0; q < nd; ++q) k += (dtS[q] < a) ? 1 : 0;
        float z[16];
        #pragma unroll
        for (int t = 0; t < 16; ++t) z[t] = b2[c16 + t];
        float d2 = d * d;
        float cC = d * TW + d2;
        #pragma unroll
        for (int t = 0; t < 16; ++t) z[t] += cC * tabL[c16 + t];
        float run = 0.f, runW = 0.f;
        for (int q = 0; q < nd; ++q) {
            run += histA[(size_t)q * N_NODES + n];
            if (needW) runW += histW[(size_t)q * N_NODES + n];
            bool act = (q < k);
            float cWp = d * (TA - run) + (act ? d2 * a : 0.f);
            float cWm = d * run + (act ? 0.f : d2 * a);
            float cBp = d * (TW - runW) + (act ? d2 : 0.f);
            float cBm = d * runW + (act ? 0.f : d2);
            int base = (1 + 4 * q) * HDIM + c16;
            #pragma unroll
            for (int t = 0; t < 16; ++t)
                z[t] += cWp * tabL[base + t] + cWm * tabL[base + HDIM + t]
                      + cBp * tabL[base + 2 * HDIM + t] + cBm * tabL[base + 3 * HDIM + t];
        }
        #pragma unroll
        for (int t = 0; t < 16; ++t) h2s[nl * 65 + c16 + t] = fmaxf(z[t], 0.f);
    } else {
        // general path (correctness-only): stage areg slices through h2s
        float zz[16];
        #pragma unroll
        for (int t = 0; t < 16; ++t) zz[t] = 0.f;
        int b = n >> CBSH;                           // uniform across block
        int myld = n & (CBN - 1);
        for (int w = 0; w < NWG; ++w) {
            int st = w * EPW + wgpre[w * NCB + b];
            int cb = wgcnt[w * NCB + b];
            for (int i = 0; i < cb; ++i) {
                unsigned ww = sorted[st + i];
                if ((int)(ww & (CBN - 1)) == myld) {
                    float2 t2 = ad[ww >> CBSH];
                    #pragma unroll
                    for (int t = 0; t < 16; ++t)
                        zz[t] += t2.y * fmaxf(t2.x * pw1[c16 + t] + pb1[c16 + t], 0.f);
                }
            }
        }
        #pragma unroll
        for (int t = 0; t < 16; ++t)
            zz[t] = d * zz[t] + d * d * fmaxf(a * pw1[c16 + t] + pb1[c16 + t], 0.f);
        #pragma unroll
        for (int t = 0; t < 16; ++t) h2s[nl * 65 + c16 + t] = zz[t];   // areg staging
        __syncthreads();
        float z[16];
        #pragma unroll
        for (int t = 0; t < 16; ++t) z[t] = b2[c16 + t];
        for (int jj = 0; jj < HDIM; ++jj) {
            float av = h2s[nl * 65 + jj];
            #pragma unroll
            for (int t = 0; t < 16; ++t) z[t] += av * w2p[jj * HDIM + c16 + t];
        }
        __syncthreads();
        #pragma unroll
        for (int t = 0; t < 16; ++t) h2s[nl * 65 + c16 + t] = fmaxf(z[t], 0.f);
    }

    __syncthreads();
    int i0 = cg * 16, i1 = min(i0 + 16, nvalid);
    float accP = 0.f; int gcur = -1, runC = 0;
    for (int i = i0; i < i1; ++i) {
        int g = batch[n0 + i];
        float v = h2s[i * 65 + nl];
        if (g != gcur) {
            if (gcur >= 0) {
                atomicAdd(&pool[(size_t)gcur * HDIM + nl], accP);
                if (nl == 0) atomicAdd(&cnt[gcur], runC);
            }
            gcur = g; accP = 0.f; runC = 0;
        }
        accP += v; ++runC;
    }
    if (gcur >= 0) {
        atomicAdd(&pool[(size_t)gcur * HDIM + nl], accP);
        if (nl == 0) atomicAdd(&cnt[gcur], runC);
    }
}

// ---------------- final MLP per graph
__global__ void k7_mlp(const float* __restrict__ pool, const int* __restrict__ cnt,
                       const float* __restrict__ fW1, const float* __restrict__ fb1,
                       const float* __restrict__ fW2, const float* __restrict__ fb2,
                       float* __restrict__ out) {
    __shared__ float p[HDIM];
    __shared__ float tt[32];
    int g = blockIdx.x;
    int tid = threadIdx.x;
    float c = fmaxf((float)cnt[g], 1.f);
    p[tid] = pool[g * HDIM + tid] / c;
    __syncthreads();
    if (tid < 32) {
        float acc = fb1[tid];
        #pragma unroll
        for (int j = 0; j < HDIM; ++j) acc += p[j] * fW1[j * 32 + tid];
        tt[tid] = fmaxf(acc, 0.f);
    }
    __syncthreads();
    if (tid < 7) {
        float acc = fb2[tid];
        #pragma unroll
        for (int i = 0; i < 32; ++i) acc += tt[i] * fW2[i * 7 + tid];
        out[g * 7 + tid] = acc;
    }
}

// =================== fallback path (round-1 kernels, if ws too small) ===================
__global__ void kf1_deg(const int* __restrict__ dst, int* __restrict__ deg) {
    int e = blockIdx.x * blockDim.x + threadIdx.x;
    if (e < N_EDGES) atomicAdd(&deg[dst[e]], 1);
}
__global__ void kf2_dis(const int* __restrict__ deg, const float* __restrict__ x,
                        float* __restrict__ dis, float* __restrict__ agg1) {
    int n = blockIdx.x * blockDim.x + threadIdx.x;
    if (n < N_NODES) {
        float d = (float)(deg[n] + 1);
        dis[n] = rsqrtf(d);
        agg1[n] = x[n] / d;
    }
}
__global__ void kf3_agg1(const int* __restrict__ src, const int* __restrict__ dst,
                         const float* __restrict__ dis, const float* __restrict__ x,
                         float* __restrict__ agg1) {
    int e = blockIdx.x * blockDim.x + threadIdx.x;
    if (e < N_EDGES) {
        int s = src[e], d = dst[e];
        atomicAdd(&agg1[d], dis[s] * dis[d] * x[s]);
    }
}
__global__ void kf4_agg2init(const float* __restrict__ agg1, const float* __restrict__ dis,
                             const float* __restrict__ W1, const float* __restrict__ b1,
                             float* __restrict__ agg2) {
    int i = blockIdx.x * blockDim.x + threadIdx.x;
    if (i < N_NODES * HDIM) {
        int n = i >> 6, j = i & 63;
        float h = fmaxf(agg1[n] * W1[j] + b1[j], 0.f);
        float r = dis[n];
        agg2[i] = r * r * h;
    }
}
__global__ void kf5_edge(const int* __restrict__ src, const int* __restrict__ dst,
                         const float* __restrict__ dis, const float* __restrict__ agg1,
                         const float* __restrict__ W1, const float* __restrict__ b1,
                         float* __restrict__ agg2) {
    int t = blockIdx.x * blockDim.x + threadIdx.x;
    int e = t >> 6, j = t & 63;
    if (e < N_EDGES) {
        int s = src[e], d = dst[e];
        float w = dis[s] * dis[d];
        float h = fmaxf(agg1[s] * W1[j] + b1[j], 0.f);
        atomicAdd(&agg2[d * HDIM + j], w * h);
    }
}
__global__ void kf6_pool(const float* __restrict__ agg2, const float* __restrict__ W2,
                         const float* __restrict__ b2, const int* __restrict__ batch,
                         float* __restrict__ pool, int* __restrict__ cnt) {
    __shared__ float w2s[HDIM * HDIM];
    int tid = threadIdx.x;
    for (int i = tid; i < HDIM * HDIM; i += blockDim.x) w2s[i] = W2[i];
    __syncthreads();
    int lane = tid & 63, wid = tid >> 6;
    int nwaves = gridDim.x * 4;
    for (int n = blockIdx.x * 4 + wid; n < N_NODES; n += nwaves) {
        float av  = agg2[n * HDIM + lane];
        float acc = b2[lane];
        #pragma unroll
        for (int k = 0; k < HDIM; ++k)
            acc += __shfl(av, k, 64) * w2s[k * HDIM + lane];
        acc = fmaxf(acc, 0.f);
        int g = batch[n];
        atomicAdd(&pool[g * HDIM + lane], acc);
        if (lane == 0) atomicAdd(&cnt[g], 1);
    }
}

// ----------------------------------------------------------------------------
extern "C" void kernel_launch(void* const* d_in, const int* in_sizes, int n_in,
                              void* d_out, int out_size, void* d_ws, size_t ws_size,
                              hipStream_t stream) {
    const float* x    = (const float*)d_in[0];
    const int*   ei   = (const int*)  d_in[1];
    const int*   batch= (const int*)  d_in[2];
    const float* W1   = (const float*)d_in[3];
    const float* b1   = (const float*)d_in[4];
    const float* W2   = (const float*)d_in[5];
    const float* b2   = (const float*)d_in[6];
    const float* fW1  = (const float*)d_in[7];
    const float* fb1  = (const float*)d_in[8];
    const float* fW2  = (const float*)d_in[9];
    const float* fb2  = (const float*)d_in[10];
    const int* src = ei;
    const int* dst = ei + N_EDGES;
    float* out = (float*)d_out;

    size_t off = 0;
    auto take = [&](size_t bytes) { size_t o = off; off = (off + bytes + 255) & ~(size_t)255; return o; };
    char* base = (char*)d_ws;
    int*     deg   = (int*)     (base + take((size_t)N_NODES * 4));
    float*   pool  = (float*)   (base + take((size_t)G_GRAPHS * HDIM * 4));
    int*     cnt   = (int*)     (base + take((size_t)G_GRAPHS * 4));
    float*   dis   = (float*)   (base + take((size_t)N_NODES * 4));
    float*   u     = (float*)   (base + take((size_t)N_NODES * 4));
    float*   q     = (float*)   (base + take((size_t)N_NODES * 4));
    float2*  ad    = (float2*)  (base + take((size_t)N_NODES * 8));
    float*   dt    = (float*)   (base + take(HDIM * 4));
    int*     meta  = (int*)     (base + take(64));
    float*   pw1   = (float*)   (base + take(HDIM * 4));
    float*   pb1   = (float*)   (base + take(HDIM * 4));
    float*   w2p   = (float*)   (base + take(HDIM * HDIM * 4));
    float*   tabs  = (float*)   (base + take((size_t)MAXROWS * HDIM * 4));
    int*     wgcnt = (int*)     (base + take((size_t)NWG * NCB * 4));
    int*     wgpre = (int*)     (base + take((size_t)NWG * NCB * 4));
    size_t sorted_off = off;
    unsigned* sorted = (unsigned*)(base + take((size_t)N_EDGES * 4));
    float*   histA = (float*)   (base + take((size_t)7 * N_NODES * 4));
    float*   histW = (float*)   (base + take((size_t)7 * N_NODES * 4));
    size_t need_fast = off;

    if (ws_size >= need_fast) {
        kBZ   <<<NWG + ZBLK, 256, 0, stream>>>(src, dst, sorted, wgcnt, wgpre,
                                               W1, b1, W2, dt, meta, pw1, pb1, w2p, tabs,
                                               deg, q, pool, cnt, histA, histW);
        kdeg2 <<<NCB * SPL, RTHR, 0, stream>>>(sorted, wgcnt, wgpre, deg);
        k2_dis<<<(N_NODES + 255) / 256, 256, 0, stream>>>(deg, x, dis, u);
        kq3   <<<NCB * SPL, RTHR, 0, stream>>>(sorted, wgcnt, wgpre, u, q);
        k3b   <<<(N_NODES + 255) / 256, 256, 0, stream>>>(deg, x, dis, q, ad);
        khist <<<NCB * SPL, RTHR, 0, stream>>>(sorted, wgcnt, wgpre, ad, dt, meta, histA, histW);
        knode <<<(N_NODES + 63) / 64, 256, 0, stream>>>(histA, histW, meta, dt, tabs,
                                                        pw1, pb1, w2p, ad, b2, batch,
                                                        sorted, wgcnt, wgpre, pool, cnt);
        k7_mlp<<<G_GRAPHS, 64, 0, stream>>>(pool, cnt, fW1, fb1, fW2, fb2, out);
    } else {
        // fallback: R1 pipeline; agg1 in u, agg2 in the sorted/hist region
        float* agg1 = u;
        float* agg2 = (float*)(base + sorted_off);
        hipMemsetAsync(deg, 0, (size_t)N_NODES * 4, stream);
        hipMemsetAsync(pool, 0, (size_t)G_GRAPHS * HDIM * 4 + 1024, stream);
        kf1_deg<<<(N_EDGES + 255) / 256, 256, 0, stream>>>(dst, deg);
        kf2_dis<<<(N_NODES + 255) / 256, 256, 0, stream>>>(deg, x, dis, agg1);
        kf3_agg1<<<(N_EDGES + 255) / 256, 256, 0, stream>>>(src, dst, dis, x, agg1);
        kf4_agg2init<<<(N_NODES * HDIM + 255) / 256, 256, 0, stream>>>(agg1, dis, W1, b1, agg2);
        int k5_blocks = (int)(((long long)N_EDGES * HDIM + 255) / 256);
        kf5_edge<<<k5_blocks, 256, 0, stream>>>(src, dst, dis, agg1, W1, b1, agg2);
        kf6_pool<<<2048, 256, 0, stream>>>(agg2, W2, b2, batch, pool, cnt);
        k7_mlp<<<G_GRAPHS, 64, 0, stream>>>(pool, cnt, fW1, fb1, fW2, fb2, out);
    }
}

// Round 19
// 125.973 us; speedup vs baseline: 1.0157x; 1.0096x over previous
//
#include <hip/hip_runtime.h>

#define N_NODES 100000
#define N_EDGES 3200000
#define G_GRAPHS 512
#define HDIM 64
#define CBSH 11                 // 2048 nodes per coarse bucket
#define CBN 2048
#define NCB ((N_NODES + CBN - 1) / CBN)   // 49
#define EPW 4096                // edges per workgroup segment
#define NWG ((N_EDGES + EPW - 1) / EPW)   // 782
#define BTHR 512                // binning block threads (8 waves)
#define NWV 8                   // waves per binning block
#define SPL 8                   // splits per bucket in edge-reduce kernels
#define RTHR 512                // threads in reduce kernels (8 waves)
#define WPS ((NWG + SPL - 1) / SPL)       // 98 wgs per split
#define MAXROWS 25              // 1 + 4*6 table rows
#define ZBLK 512                // zero/prep blocks appended to kBZ

// ---------------- kBZ: fused {edge binning | prep | zero}, 512-thread blocks
__global__ __launch_bounds__(BTHR) void kBZ(const int* __restrict__ src,
                                            const int* __restrict__ dst,
                                            unsigned* __restrict__ sorted,
                                            int* __restrict__ wgcnt,
                                            int* __restrict__ wgpre,
                                            const float* __restrict__ W1,
                                            const float* __restrict__ b1,
                                            const float* __restrict__ W2,
                                            float* __restrict__ dt, int* __restrict__ meta,
                                            float* __restrict__ pw1, float* __restrict__ pb1,
                                            float* __restrict__ w2p, float* __restrict__ tabs,
                                            int* __restrict__ deg, float* __restrict__ q,
                                            float* __restrict__ pool, int* __restrict__ cnt,
                                            float* __restrict__ histA, float* __restrict__ histW) {
    int tid = threadIdx.x;
    if (blockIdx.x < NWG) {
        __shared__ int hist[NWV][NCB];
        __shared__ int basep[NWV][NCB];
        __shared__ unsigned sbuf[EPW];     // 16 KB
        int wv = tid >> 6;
        int w = blockIdx.x;
        int e0 = w * EPW;
        int ecnt = min(EPW, N_EDGES - e0);           // multiple of 4
        int nv4 = ecnt >> 2;
        for (int i = tid; i < NWV * NCB; i += BTHR) (&hist[0][0])[i] = 0;
        __syncthreads();
        const uint4* dst4 = reinterpret_cast<const uint4*>(dst + e0);
        const uint4* src4 = reinterpret_cast<const uint4*>(src + e0);
        // phase 1: histogram (keep nothing); 2 iterations/thread
        for (int v = tid; v < nv4; v += BTHR) {
            uint4 dv = dst4[v];
            atomicAdd(&hist[wv][dv.x >> CBSH], 1);
            atomicAdd(&hist[wv][dv.y >> CBSH], 1);
            atomicAdd(&hist[wv][dv.z >> CBSH], 1);
            atomicAdd(&hist[wv][dv.w >> CBSH], 1);
        }
        __syncthreads();
        if (tid < 64) {                              // wave 0: totals + scan + wave bases
            int h[NWV], tot = 0;
            #pragma unroll
            for (int r = 0; r < NWV; ++r) {
                h[r] = (tid < NCB) ? hist[r][tid] : 0;
                tot += h[r];
            }
            int v = tot;
            #pragma unroll
            for (int off = 1; off < 64; off <<= 1) {
                int uu = __shfl_up(v, off, 64);
                if (tid >= off) v += uu;
            }
            if (tid < NCB) {
                int base = v - tot;                  // exclusive prefix
                #pragma unroll
                for (int r = 0; r < NWV; ++r) { basep[r][tid] = base; base += h[r]; }
                wgcnt[w * NCB + tid] = tot;
                wgpre[w * NCB + tid] = v - tot;
            }
        }
        __syncthreads();
        // phase 3: reload (L2-hot) and scatter into sbuf
        for (int v = tid; v < nv4; v += BTHR) {
            uint4 dv = dst4[v];
            uint4 sv = src4[v];
            int b, pos;
            b = (int)(dv.x >> CBSH); pos = atomicAdd(&basep[wv][b], 1);
            sbuf[pos] = (sv.x << CBSH) | (dv.x & (CBN - 1));
            b = (int)(dv.y >> CBSH); pos = atomicAdd(&basep[wv][b], 1);
            sbuf[pos] = (sv.y << CBSH) | (dv.y & (CBN - 1));
            b = (int)(dv.z >> CBSH); pos = atomicAdd(&basep[wv][b], 1);
            sbuf[pos] = (sv.z << CBSH) | (dv.z & (CBN - 1));
            b = (int)(dv.w >> CBSH); pos = atomicAdd(&basep[wv][b], 1);
            sbuf[pos] = (sv.w << CBSH) | (dv.w & (CBN - 1));
        }
        __syncthreads();
        uint4* out4 = reinterpret_cast<uint4*>(sorted + e0);
        const uint4* sb4 = reinterpret_cast<const uint4*>(sbuf);
        for (int i = tid; i < nv4; i += BTHR) out4[i] = sb4[i];
        return;
    }
    // ---- prep branch (first 16 zero-blocks) + zero branch (all zero-blocks)
    int zb = blockIdx.x - NWG;                           // 0..ZBLK-1
    if (zb < 16) {
        __shared__ float ts[HDIM], srt[HDIM];
        __shared__ int isnew[HDIM], rr[HDIM], kpermS[HDIM], rankS[HDIM];
        __shared__ int ndS;
        if (tid < HDIM) {
            float w1 = W1[tid], bb = b1[tid];
            ts[tid] = (w1 != 0.f) ? (-bb / w1) : -1e30f;
        }
        __syncthreads();
        if (tid < HDIM) {
            float tj = ts[tid];
            int r = 0;
            for (int i = 0; i < HDIM; ++i) {
                float ti = ts[i];
                if (ti < tj || (ti == tj && i < tid)) r++;   // stable rank
            }
            rr[tid] = r;
            srt[r] = tj;
            kpermS[r] = tid;
        }
        __syncthreads();
        if (tid < HDIM) {
            int r = rr[tid];
            isnew[r] = (r == 0) || (srt[r] != srt[r - 1]);
        }
        __syncthreads();
        if (tid < HDIM) {
            int r = rr[tid];
            int didx = 0;
            for (int qq = 0; qq <= r; ++qq) didx += isnew[qq];
            didx -= 1;
            rankS[tid] = didx;
            if (zb == 0 && isnew[r]) dt[didx] = srt[r];
        }
        if (tid == 0) {
            int nd = 0;
            for (int qq = 0; qq < HDIM; ++qq) nd += isnew[qq];
            ndS = nd;
            if (zb == 0) {
                int nw = 0;
                for (int qq = 0; qq < HDIM; ++qq) nw |= (b1[qq] != 0.f) ? 1 : 0;
                meta[0] = nd; meta[1] = nw;
            }
        }
        __syncthreads();
        int nd = ndS;
        if (zb == 0 && tid < HDIM) {
            int pj = kpermS[tid];
            pw1[tid] = W1[pj]; pb1[tid] = b1[pj];
        }
        int i = zb * BTHR + tid;
        if (i < HDIM * HDIM) {
            int r = i >> 6, j = i & 63;
            w2p[i] = W2[kpermS[r] * HDIM + j];
        }
        if (nd <= 6 && i < (1 + 4 * nd) * HDIM) {
            int r = i >> 6, j = i & 63;
            float acc = 0.f;
            if (r == 0) {
                for (int jj = 0; jj < HDIM; ++jj)
                    if (W1[jj] == 0.f) acc += fmaxf(b1[jj], 0.f) * W2[jj * HDIM + j];
            } else {
                int qq = (r - 1) >> 2, c = (r - 1) & 3;
                for (int jj = 0; jj < HDIM; ++jj) {
                    if (rankS[jj] != qq) continue;
                    float w1 = W1[jj], bb = b1[jj];
                    float wr = W2[jj * HDIM + j];
                    if      (c == 0 && w1 > 0.f) acc += w1 * wr;
                    else if (c == 1 && w1 < 0.f) acc += w1 * wr;
                    else if (c == 2 && w1 > 0.f) acc += bb * wr;
                    else if (c == 3 && w1 < 0.f) acc += bb * wr;
                }
            }
            tabs[i] = acc;
        }
    }
    // zero (grid-stride over zero-blocks)
    size_t gtid = (size_t)zb * BTHR + tid;
    size_t stride = (size_t)ZBLK * BTHR;
    for (size_t i = gtid; i < N_NODES; i += stride) { deg[i] = 0; q[i] = 0.f; }
    for (size_t i = gtid; i < G_GRAPHS * HDIM; i += stride) pool[i] = 0.f;
    for (size_t i = gtid; i < G_GRAPHS; i += stride) cnt[i] = 0;
    size_t nh = (size_t)7 * N_NODES;
    for (size_t i = gtid; i < nh; i += stride) { histA[i] = 0.f; histW[i] = 0.f; }
}

// helper macro: iterate this split's runs for bucket b, wave-per-run
#define FOR_RUNS(BODY)                                                        \
    {                                                                         \
        int wv = tid >> 6, ln = tid & 63;                                     \
        int w0 = sp * WPS, w1e = min(w0 + WPS, NWG);                          \
        for (int w = w0 + wv; w < w1e; w += (RTHR / 64)) {                    \
            int st = w * EPW + wgpre[w * NCB + b];                            \
            int cb = wgcnt[w * NCB + b];                                      \
            for (int i = ln; i < cb; i += 64) { unsigned ww = sorted[st + i]; BODY } \
        }                                                                     \
    }

// ---------------- kdeg2: split LDS degree count + coalesced atomic merge
__global__ __launch_bounds__(RTHR) void kdeg2(const unsigned* __restrict__ sorted,
                                              const int* __restrict__ wgcnt,
                                              const int* __restrict__ wgpre,
                                              int* __restrict__ deg) {
    __shared__ int dcnt[CBN];
    int b = blockIdx.x / SPL, sp = blockIdx.x % SPL, tid = threadIdx.x;
    for (int i = tid; i < CBN; i += RTHR) dcnt[i] = 0;
    __syncthreads();
    FOR_RUNS( atomicAdd(&dcnt[ww & (CBN - 1)], 1); )
    __syncthreads();
    int nb = b * CBN;
    for (int i = tid; i < CBN; i += RTHR) {
        int c = dcnt[i];
        if (c && nb + i < N_NODES) atomicAdd(&deg[nb + i], c);
    }
}

// ---------------- k2_dis: dis = rsqrt(deg+1); u = dis*x
__global__ void k2_dis(const int* __restrict__ deg, const float* __restrict__ x,
                       float* __restrict__ dis, float* __restrict__ u) {
    int n = blockIdx.x * blockDim.x + threadIdx.x;
    if (n < N_NODES) {
        float d = rsqrtf((float)(deg[n] + 1));
        dis[n] = d;
        u[n] = d * x[n];
    }
}

// ---------------- kq3: split LDS layer-1 reduce + coalesced atomic merge
__global__ __launch_bounds__(RTHR) void kq3(const unsigned* __restrict__ sorted,
                                            const int* __restrict__ wgcnt,
                                            const int* __restrict__ wgpre,
                                            const float* __restrict__ u,
                                            float* __restrict__ q) {
    __shared__ float qL[CBN];
    int b = blockIdx.x / SPL, sp = blockIdx.x % SPL, tid = threadIdx.x;
    for (int i = tid; i < CBN; i += RTHR) qL[i] = 0.f;
    __syncthreads();
    FOR_RUNS( atomicAdd(&qL[ww & (CBN - 1)], u[ww >> CBSH]); )
    __syncthreads();
    int nb = b * CBN;
    for (int i = tid; i < CBN; i += RTHR) {
        float v = qL[i];
        if (v != 0.f && nb + i < N_NODES) atomicAdd(&q[nb + i], v);
    }
}

// ---------------- k3b: finalize (agg1, dis) pack
__global__ void k3b(const int* __restrict__ deg, const float* __restrict__ x,
                    const float* __restrict__ dis, const float* __restrict__ q,
                    float2* __restrict__ ad) {
    int n = blockIdx.x * blockDim.x + threadIdx.x;
    if (n < N_NODES) {
        float d = dis[n];
        ad[n] = make_float2(d * q[n] + x[n] / (float)(deg[n] + 1), d);
    }
}

// ---------------- khist: split LDS bucket-sums (single variant, 7 planes, ad gather)
__global__ __launch_bounds__(RTHR) void khist(const unsigned* __restrict__ sorted,
                                              const int* __restrict__ wgcnt,
                                              const int* __restrict__ wgpre,
                                              const float2* __restrict__ ad,
                                              const float* __restrict__ dt,
                                              const int* __restrict__ meta,
                                              float* __restrict__ histA,
                                              float* __restrict__ histW) {
    __shared__ float bA[7 * CBN];          // 56 KB
    __shared__ float dtS[8];
    int nd = meta[0], needW = meta[1];
    if (nd > 6) return;                    // knode general path covers
    int b = blockIdx.x / SPL, sp = blockIdx.x % SPL, tid = threadIdx.x;
    if (tid < 8) dtS[tid] = (tid < nd) ? dt[tid] : 3.4e38f;
    int nb = b * CBN;
    int nparts = 1 + (needW ? 1 : 0);
    for (int part = 0; part < nparts; ++part) {
        for (int i = tid; i < (nd + 1) * CBN; i += RTHR) bA[i] = 0.f;
        __syncthreads();
        FOR_RUNS(
            float2 t = ad[ww >> CBSH];
            float a = t.x;
            int k = 0;
            _Pragma("unroll")
            for (int qq = 0; qq < 6; ++qq) k += (dtS[qq] < a) ? 1 : 0;
            atomicAdd(&bA[k * CBN + (ww & (CBN - 1))], part ? t.y : t.y * a);
        )
        __syncthreads();
        float* H = part ? histW : histA;
        for (int k = 0; k <= nd; ++k)
            for (int i = tid; i < CBN; i += RTHR) {
                float v = bA[k * CBN + i];
                if (v != 0.f && nb + i < N_NODES)
                    atomicAdd(&H[(size_t)k * N_NODES + nb + i], v);
            }
        __syncthreads();
    }
}

// ---- knode: fast table-folded path (nd<=6) + LDS-staged general path (nd>6)
__global__ __launch_bounds__(256) void knode(
        const float* __restrict__ histA, const float* __restrict__ histW,
        const int* __restrict__ meta, const float* __restrict__ dt,
        const float* __restrict__ tabs,
        const float* __restrict__ pw1, const float* __restrict__ pb1,
        const float* __restrict__ w2p,
        const float2* __restrict__ ad, const float* __restrict__ b2,
        const int* __restrict__ batch,
        const unsigned* __restrict__ sorted, const int* __restrict__ wgcnt,
        const int* __restrict__ wgpre,
        float* __restrict__ pool, int* __restrict__ cnt) {
    __shared__ float h2s[HDIM * 65];
    __shared__ float tabL[MAXROWS * HDIM];
    __shared__ float dtS[8];
    int tid = threadIdx.x;
    int nl = tid & 63, cg = tid >> 6;
    int n0 = blockIdx.x * 64;
    int nvalid = min(64, N_NODES - n0);
    int n = n0 + min(nl, nvalid - 1);
    int nd = meta[0], needW = meta[1];
    float2 adn = ad[n];
    float a = adn.x, d = adn.y;
    int c16 = cg * 16;

    if (nd <= 6) {
        int nrows = 1 + 4 * nd;
        for (int i = tid; i < nrows * HDIM; i += 256) tabL[i] = tabs[i];
        if (tid < nd) dtS[tid] = dt[tid];
        __syncthreads();
        float TA = 0.f, TW = 0.f;
        for (int bq = 0; bq <= nd; ++bq) {
            TA += histA[(size_t)bq * N_NODES + n];
            if (needW) TW += histW[(size_t)bq * N_NODES + n];
        }
        int k = 0;
        for (int q = 0; q < nd; ++q) k += (dtS[q] < a) ? 1 : 0;
        float z[16];
        #pragma unroll
        for (int t = 0; t < 16; ++t) z[t] = b2[c16 + t];
        float d2 = d * d;
        float cC = d * TW + d2;
        #pragma unroll
        for (int t = 0; t < 16; ++t) z[t] += cC * tabL[c16 + t];
        float run = 0.f, runW = 0.f;
        for (int q = 0; q < nd; ++q) {
            run += histA[(size_t)q * N_NODES + n];
            if (needW) runW += histW[(size_t)q * N_NODES + n];
            bool act = (q < k);
            float cWp = d * (TA - run) + (act ? d2 * a : 0.f);
            float cWm = d * run + (act ? 0.f : d2 * a);
            float cBp = d * (TW - runW) + (act ? d2 : 0.f);
            float cBm = d * runW + (act ? 0.f : d2);
            int base = (1 + 4 * q) * HDIM + c16;
            #pragma unroll
            for (int t = 0; t < 16; ++t)
                z[t] += cWp * tabL[base + t] + cWm * tabL[base + HDIM + t]
                      + cBp * tabL[base + 2 * HDIM + t] + cBm * tabL[base + 3 * HDIM + t];
        }
        #pragma unroll
        for (int t = 0; t < 16; ++t) h2s[nl * 65 + c16 + t] = fmaxf(z[t], 0.f);
    } else {
        // general path (correctness-only): stage areg slices through h2s
        float zz[16];
        #pragma unroll
        for (int t = 0; t < 16; ++t) zz[t] = 0.f;
        int b = n >> CBSH;                           // uniform across block
        int myld = n & (CBN - 1);
        for (int w = 0; w < NWG; ++w) {
            int st = w * EPW + wgpre[w * NCB + b];
            int cb = wgcnt[w * NCB + b];
            for (int i = 0; i < cb; ++i) {
                unsigned ww = sorted[st + i];
                if ((int)(ww & (CBN - 1)) == myld) {
                    float2 t2 = ad[ww >> CBSH];
                    #pragma unroll
                    for (int t = 0; t < 16; ++t)
                        zz[t] += t2.y * fmaxf(t2.x * pw1[c16 + t] + pb1[c16 + t], 0.f);
                }
            }
        }
        #pragma unroll
        for (int t = 0; t < 16; ++t)
            zz[t] = d * zz[t] + d * d * fmaxf(a * pw1[c16 + t] + pb1[c16 + t], 0.f);
        #pragma unroll
        for (int t = 0; t < 16; ++t) h2s[nl * 65 + c16 + t] = zz[t];   // areg staging
        __syncthreads();
        float z[16];
        #pragma unroll
        for (int t = 0; t < 16; ++t) z[t] = b2[c16 + t];
        for (int jj = 0; jj < HDIM; ++jj) {
            float av = h2s[nl * 65 + jj];
            #pragma unroll
            for (int t = 0; t < 16; ++t) z[t] += av * w2p[jj * HDIM + c16 + t];
        }
        __syncthreads();
        #pragma unroll
        for (int t = 0; t < 16; ++t) h2s[nl * 65 + c16 + t] = fmaxf(z[t], 0.f);
    }

    __syncthreads();
    int i0 = cg * 16, i1 = min(i0 + 16, nvalid);
    float accP = 0.f; int gcur = -1, runC = 0;
    for (int i = i0; i < i1; ++i) {
        int g = batch[n0 + i];
        float v = h2s[i * 65 + nl];
        if (g != gcur) {
            if (gcur >= 0) {
                atomicAdd(&pool[(size_t)gcur * HDIM + nl], accP);
                if (nl == 0) atomicAdd(&cnt[gcur], runC);
            }
            gcur = g; accP = 0.f; runC = 0;
        }
        accP += v; ++runC;
    }
    if (gcur >= 0) {
        atomicAdd(&pool[(size_t)gcur * HDIM + nl], accP);
        if (nl == 0) atomicAdd(&cnt[gcur], runC);
    }
}

// ---------------- final MLP per graph
__global__ void k7_mlp(const float* __restrict__ pool, const int* __restrict__ cnt,
                       const float* __restrict__ fW1, const float* __restrict__ fb1,
                       const float* __restrict__ fW2, const float* __restrict__ fb2,
                       float* __restrict__ out) {
    __shared__ float p[HDIM];
    __shared__ float tt[32];
    int g = blockIdx.x;
    int tid = threadIdx.x;
    float c = fmaxf((float)cnt[g], 1.f);
    p[tid] = pool[g * HDIM + tid] / c;
    __syncthreads();
    if (tid < 32) {
        float acc = fb1[tid];
        #pragma unroll
        for (int j = 0; j < HDIM; ++j) acc += p[j] * fW1[j * 32 + tid];
        tt[tid] = fmaxf(acc, 0.f);
    }
    __syncthreads();
    if (tid < 7) {
        float acc = fb2[tid];
        #pragma unroll
        for (int i = 0; i < 32; ++i) acc += tt[i] * fW2[i * 7 + tid];
        out[g * 7 + tid] = acc;
    }
}

// =================== fallback path (round-1 kernels, if ws too small) ===================
__global__ void kf1_deg(const int* __restrict__ dst, int* __restrict__ deg) {
    int e = blockIdx.x * blockDim.x + threadIdx.x;
    if (e < N_EDGES) atomicAdd(&deg[dst[e]], 1);
}
__global__ void kf2_dis(const int* __restrict__ deg, const float* __restrict__ x,
                        float* __restrict__ dis, float* __restrict__ agg1) {
    int n = blockIdx.x * blockDim.x + threadIdx.x;
    if (n < N_NODES) {
        float d = (float)(deg[n] + 1);
        dis[n] = rsqrtf(d);
        agg1[n] = x[n] / d;
    }
}
__global__ void kf3_agg1(const int* __restrict__ src, const int* __restrict__ dst,
                         const float* __restrict__ dis, const float* __restrict__ x,
                         float* __restrict__ agg1) {
    int e = blockIdx.x * blockDim.x + threadIdx.x;
    if (e < N_EDGES) {
        int s = src[e], d = dst[e];
        atomicAdd(&agg1[d], dis[s] * dis[d] * x[s]);
    }
}
__global__ void kf4_agg2init(const float* __restrict__ agg1, const float* __restrict__ dis,
                             const float* __restrict__ W1, const float* __restrict__ b1,
                             float* __restrict__ agg2) {
    int i = blockIdx.x * blockDim.x + threadIdx.x;
    if (i < N_NODES * HDIM) {
        int n = i >> 6, j = i & 63;
        float h = fmaxf(agg1[n] * W1[j] + b1[j], 0.f);
        float r = dis[n];
        agg2[i] = r * r * h;
    }
}
__global__ void kf5_edge(const int* __restrict__ src, const int* __restrict__ dst,
                         const float* __restrict__ dis, const float* __restrict__ agg1,
                         const float* __restrict__ W1, const float* __restrict__ b1,
                         float* __restrict__ agg2) {
    int t = blockIdx.x * blockDim.x + threadIdx.x;
    int e = t >> 6, j = t & 63;
    if (e < N_EDGES) {
        int s = src[e], d = dst[e];
        float w = dis[s] * dis[d];
        float h = fmaxf(agg1[s] * W1[j] + b1[j], 0.f);
        atomicAdd(&agg2[d * HDIM + j], w * h);
    }
}
__global__ void kf6_pool(const float* __restrict__ agg2, const float* __restrict__ W2,
                         const float* __restrict__ b2, const int* __restrict__ batch,
                         float* __restrict__ pool, int* __restrict__ cnt) {
    __shared__ float w2s[HDIM * HDIM];
    int tid = threadIdx.x;
    for (int i = tid; i < HDIM * HDIM; i += blockDim.x) w2s[i] = W2[i];
    __syncthreads();
    int lane = tid & 63, wid = tid >> 6;
    int nwaves = gridDim.x * 4;
    for (int n = blockIdx.x * 4 + wid; n < N_NODES; n += nwaves) {
        float av  = agg2[n * HDIM + lane];
        float acc = b2[lane];
        #pragma unroll
        for (int k = 0; k < HDIM; ++k)
            acc += __shfl(av, k, 64) * w2s[k * HDIM + lane];
        acc = fmaxf(acc, 0.f);
        int g = batch[n];
        atomicAdd(&pool[g * HDIM + lane], acc);
        if (lane == 0) atomicAdd(&cnt[g], 1);
    }
}

// ----------------------------------------------------------------------------
extern "C" void kernel_launch(void* const* d_in, const int* in_sizes, int n_in,
                              void* d_out, int out_size, void* d_ws, size_t ws_size,
                              hipStream_t stream) {
    const float* x    = (const float*)d_in[0];
    const int*   ei   = (const int*)  d_in[1];
    const int*   batch= (const int*)  d_in[2];
    const float* W1   = (const float*)d_in[3];
    const float* b1   = (const float*)d_in[4];
    const float* W2   = (const float*)d_in[5];
    const float* b2   = (const float*)d_in[6];
    const float* fW1  = (const float*)d_in[7];
    const float* fb1  = (const float*)d_in[8];
    const float* fW2  = (const float*)d_in[9];
    const float* fb2  = (const float*)d_in[10];
    const int* src = ei;
    const int* dst = ei + N_EDGES;
    float* out = (float*)d_out;

    size_t off = 0;
    auto take = [&](size_t bytes) { size_t o = off; off = (off + bytes + 255) & ~(size_t)255; return o; };
    char* base = (char*)d_ws;
    int*     deg   = (int*)     (base + take((size_t)N_NODES * 4));
    float*   pool  = (float*)   (base + take((size_t)G_GRAPHS * HDIM * 4));
    int*     cnt   = (int*)     (base + take((size_t)G_GRAPHS * 4));
    float*   dis   = (float*)   (base + take((size_t)N_NODES * 4));
    float*   u     = (float*)   (base + take((size_t)N_NODES * 4));
    float*   q     = (float*)   (base + take((size_t)N_NODES * 4));
    float2*  ad    = (float2*)  (base + take((size_t)N_NODES * 8));
    float*   dt    = (float*)   (base + take(HDIM * 4));
    int*     meta  = (int*)     (base + take(64));
    float*   pw1   = (float*)   (base + take(HDIM * 4));
    float*   pb1   = (float*)   (base + take(HDIM * 4));
    float*   w2p   = (float*)   (base + take(HDIM * HDIM * 4));
    float*   tabs  = (float*)   (base + take((size_t)MAXROWS * HDIM * 4));
    int*     wgcnt = (int*)     (base + take((size_t)NWG * NCB * 4));
    int*     wgpre = (int*)     (base + take((size_t)NWG * NCB * 4));
    size_t sorted_off = off;
    unsigned* sorted = (unsigned*)(base + take((size_t)N_EDGES * 4));
    float*   histA = (float*)   (base + take((size_t)7 * N_NODES * 4));
    float*   histW = (float*)   (base + take((size_t)7 * N_NODES * 4));
    size_t need_fast = off;

    if (ws_size >= need_fast) {
        kBZ   <<<NWG + ZBLK, BTHR, 0, stream>>>(src, dst, sorted, wgcnt, wgpre,
                                                W1, b1, W2, dt, meta, pw1, pb1, w2p, tabs,
                                                deg, q, pool, cnt, histA, histW);
        kdeg2 <<<NCB * SPL, RTHR, 0, stream>>>(sorted, wgcnt, wgpre, deg);
        k2_dis<<<(N_NODES + 255) / 256, 256, 0, stream>>>(deg, x, dis, u);
        kq3   <<<NCB * SPL, RTHR, 0, stream>>>(sorted, wgcnt, wgpre, u, q);
        k3b   <<<(N_NODES + 255) / 256, 256, 0, stream>>>(deg, x, dis, q, ad);
        khist <<<NCB * SPL, RTHR, 0, stream>>>(sorted, wgcnt, wgpre, ad, dt, meta, histA, histW);
        knode <<<(N_NODES + 63) / 64, 256, 0, stream>>>(histA, histW, meta, dt, tabs,
                                                        pw1, pb1, w2p, ad, b2, batch,
                                                        sorted, wgcnt, wgpre, pool, cnt);
        k7_mlp<<<G_GRAPHS, 64, 0, stream>>>(pool, cnt, fW1, fb1, fW2, fb2, out);
    } else {
        // fallback: R1 pipeline; agg1 in u, agg2 in the sorted/hist region
        float* agg1 = u;
        float* agg2 = (float*)(base + sorted_off);
        hipMemsetAsync(deg, 0, (size_t)N_NODES * 4, stream);
        hipMemsetAsync(pool, 0, (size_t)G_GRAPHS * HDIM * 4 + 1024, stream);
        kf1_deg<<<(N_EDGES + 255) / 256, 256, 0, stream>>>(dst, deg);
        kf2_dis<<<(N_NODES + 255) / 256, 256, 0, stream>>>(deg, x, dis, agg1);
        kf3_agg1<<<(N_EDGES + 255) / 256, 256, 0, stream>>>(src, dst, dis, x, agg1);
        kf4_agg2init<<<(N_NODES * HDIM + 255) / 256, 256, 0, stream>>>(agg1, dis, W1, b1, agg2);
        int k5_blocks = (int)(((long long)N_EDGES * HDIM + 255) / 256);
        kf5_edge<<<k5_blocks, 256, 0, stream>>>(src, dst, dis, agg1, W1, b1, agg2);
        kf6_pool<<<2048, 256, 0, stream>>>(agg2, W2, b2, batch, pool, cnt);
        k7_mlp<<<G_GRAPHS, 64, 0, stream>>>(pool, cnt, fW1, fb1, fW2, fb2, out);
    }
}